// Round 1
// baseline (1242.253 us; speedup 1.0000x reference)
//
#include <hip/hip_runtime.h>

typedef __bf16 bf16;
typedef __bf16 bf16x8 __attribute__((ext_vector_type(8)));
typedef __bf16 bf16x4 __attribute__((ext_vector_type(4)));
typedef float  f32x4  __attribute__((ext_vector_type(4)));

__device__ __forceinline__ void async_load16(const void* g, void* l) {
    __builtin_amdgcn_global_load_lds(
        (const __attribute__((address_space(1))) void*)g,
        (__attribute__((address_space(3))) void*)l,
        16, 0, 0);
}

// ---------------- cast fp32 -> bf16, 8 elems/thread ----------------
__global__ __launch_bounds__(256) void cast_f32_bf16(
        const float* __restrict__ s, bf16* __restrict__ d, int n) {
    int i = (blockIdx.x * 256 + threadIdx.x) * 8;
    if (i >= n) return;
    f32x4 v0 = *(const f32x4*)(s + i);
    f32x4 v1 = *(const f32x4*)(s + i + 4);
    bf16x8 o;
    o[0] = (bf16)v0[0]; o[1] = (bf16)v0[1]; o[2] = (bf16)v0[2]; o[3] = (bf16)v0[3];
    o[4] = (bf16)v1[0]; o[5] = (bf16)v1[1]; o[6] = (bf16)v1[2]; o[7] = (bf16)v1[3];
    *(bf16x8*)(d + i) = o;
}

// ---------------- diagnostic fill (ws too small) ----------------
__global__ __launch_bounds__(256) void fill_f32(float* p, float v, int n) {
    int i = blockIdx.x * 256 + threadIdx.x;
    if (i < n) p[i] = v;
}

// ---------------- GEMM: C[M,N] = A[M,K] * B[N,K]^T (+bias, relu) ----------------
// m97-style: 128x128 tile, 4 waves 2x2 (each 64x64), BK=32, 16x16x32 bf16 MFMA,
// global_load_lds width-16 staging, 2-barrier K-loop.
template<int RELU, int WF32, int WBF16>
__global__ __launch_bounds__(256, 2) void gemm_bt(
        const bf16* __restrict__ A, int lda,
        const bf16* __restrict__ B, int ldb,
        const float* __restrict__ bias,
        float* __restrict__ Cf, int ldcf,
        bf16* __restrict__ Cb, int ldcb,
        int M, int N, int K) {
    (void)M; (void)N;
    __shared__ __attribute__((aligned(16))) bf16 lA[128 * 32];
    __shared__ __attribute__((aligned(16))) bf16 lB[128 * 32];

    const int t = threadIdx.x;
    const int w = t >> 6, lane = t & 63;
    const int wm = w >> 1, wn = w & 1;
    const int m0 = blockIdx.y * 128, n0 = blockIdx.x * 128;
    const int lane15 = lane & 15, quad = lane >> 4;

    f32x4 acc[4][4] = {};

    // staging: per wave, 2 chunks of 16 rows for A and for B.
    // within a chunk: lane i -> row i/4, col-elem (i&3)*8 (lane i writes LDS base+16*i)
    const int srow = lane >> 2;
    const int scol = (lane & 3) * 8;
    const int c0 = 2 * w, c1 = 2 * w + 1;
    const bf16* gA0 = A + (size_t)(m0 + c0 * 16 + srow) * lda + scol;
    const bf16* gA1 = A + (size_t)(m0 + c1 * 16 + srow) * lda + scol;
    const bf16* gB0 = B + (size_t)(n0 + c0 * 16 + srow) * ldb + scol;
    const bf16* gB1 = B + (size_t)(n0 + c1 * 16 + srow) * ldb + scol;
    bf16* lA0 = &lA[c0 * 512];
    bf16* lA1 = &lA[c1 * 512];
    bf16* lB0 = &lB[c0 * 512];
    bf16* lB1 = &lB[c1 * 512];

    // fragment read base: A row = wm*64 + i*16 + lane15, k = quad*8
    const bf16* fA = &lA[(wm * 64 + lane15) * 32 + quad * 8];
    const bf16* fB = &lB[(wn * 64 + lane15) * 32 + quad * 8];

    for (int k0 = 0; k0 < K; k0 += 32) {
        async_load16(gA0, lA0);
        async_load16(gA1, lA1);
        async_load16(gB0, lB0);
        async_load16(gB1, lB1);
        gA0 += 32; gA1 += 32; gB0 += 32; gB1 += 32;
        __syncthreads();   // drains vmcnt before any ds_read
        bf16x8 a[4], b[4];
#pragma unroll
        for (int i = 0; i < 4; i++) a[i] = *(const bf16x8*)(fA + i * 16 * 32);
#pragma unroll
        for (int j = 0; j < 4; j++) b[j] = *(const bf16x8*)(fB + j * 16 * 32);
#pragma unroll
        for (int i = 0; i < 4; i++)
#pragma unroll
            for (int j = 0; j < 4; j++)
                acc[i][j] = __builtin_amdgcn_mfma_f32_16x16x32_bf16(a[i], b[j], acc[i][j], 0, 0, 0);
        __syncthreads();   // compute done before next stage overwrites LDS
    }

    // epilogue: D[row=quad*4+r][col=lane15] per 16x16 tile
#pragma unroll
    for (int i = 0; i < 4; i++) {
        int row = m0 + wm * 64 + i * 16 + quad * 4;
#pragma unroll
        for (int j = 0; j < 4; j++) {
            int col = n0 + wn * 64 + j * 16 + lane15;
            float bv = bias ? bias[col] : 0.0f;
#pragma unroll
            for (int r = 0; r < 4; r++) {
                float v = acc[i][j][r] + bv;
                if (RELU) v = v > 0.0f ? v : 0.0f;
                if (WF32)  Cf[(size_t)(row + r) * ldcf + col] = v;
                if (WBF16) Cb[(size_t)(row + r) * ldcb + col] = (bf16)v;
            }
        }
    }
}

// ---------------- elementwise combine -> p_pre, q_pre (bf16) ----------------
__global__ __launch_bounds__(256) void combine_pq(
        const float* __restrict__ uw,          // 8192 x 4096 fp32 (u | w)
        const bf16* __restrict__ Gu, const bf16* __restrict__ Gw,
        const bf16* __restrict__ Bu, const bf16* __restrict__ Bw,
        const float* __restrict__ bias_p, const float* __restrict__ bias_q,
        bf16* __restrict__ pp, bf16* __restrict__ qp) {
    int idx = (blockIdx.x * 256 + threadIdx.x) * 4;   // into 8192x2048
    int row = idx >> 11;
    int col = idx & 2047;
    const float* up = uw + (size_t)row * 4096 + col;
    f32x4 u4 = *(const f32x4*)up;
    f32x4 w4 = *(const f32x4*)(up + 2048);
    bf16x4 gu4 = *(const bf16x4*)(Gu + idx);
    bf16x4 gw4 = *(const bf16x4*)(Gw + idx);
    bf16x4 bu4 = *(const bf16x4*)(Bu + idx);
    bf16x4 bw4 = *(const bf16x4*)(Bw + idx);
    bf16x4 po, qo;
#pragma unroll
    for (int r = 0; r < 4; r++) {
        float u = u4[r], w = w4[r];
        float gu = (float)gu4[r], gw = (float)gw4[r];
        float bu = (float)bu4[r], bw = (float)bw4[r];
        float p = u * gu + w * gw + w * bu - u * bw + bias_p[col + r];
        float q = w * gu - u * gw - u * bu - w * bw + bias_q[col + r];
        po[r] = (bf16)p;
        qo[r] = (bf16)q;
    }
    *(bf16x4*)(pp + idx) = po;
    *(bf16x4*)(qp + idx) = qo;
}

extern "C" void kernel_launch(void* const* d_in, const int* in_sizes, int n_in,
                              void* d_out, int out_size, void* d_ws, size_t ws_size,
                              hipStream_t stream) {
    (void)in_sizes; (void)n_in;
    const int BT = 8192, NX = 4096, NR = 1024, NB = 2048;

    const float* x      = (const float*)d_in[0];
    const float* W_h    = (const float*)d_in[1];
    const float* b_h    = (const float*)d_in[2];
    const float* W_h2   = (const float*)d_in[3];
    const float* b_h2   = (const float*)d_in[4];
    const float* W_y    = (const float*)d_in[5];
    const float* b_y    = (const float*)d_in[6];
    const float* G      = (const float*)d_in[7];
    const float* Bm     = (const float*)d_in[8];
    const float* bias_p = (const float*)d_in[9];
    const float* bias_q = (const float*)d_in[10];
    const float* W_p    = (const float*)d_in[11];
    const float* b_p    = (const float*)d_in[12];
    const float* W_q    = (const float*)d_in[13];
    const float* b_q    = (const float*)d_in[14];
    float* out = (float*)d_out;

    // ---- workspace layout (bytes), with lifetime-based aliasing ----
    const size_t NEED = 287309824ull;  // ~287.3 MB
    if (ws_size < NEED) {  // diagnostic: report available MB via d_out
        fill_f32<<<dim3((out_size + 255) / 256), dim3(256), 0, stream>>>(
            out, (float)(ws_size >> 20), out_size);
        return;
    }
    char* ws = (char*)d_ws;
    bf16* xb   = (bf16*)(ws + 0);            // 67.1 MB, dead after h1 GEMM
    bf16* Gu   = (bf16*)(ws + 0);            // 33.6 MB (overlays xb)
    bf16* Gw   = (bf16*)(ws + 33554432);     // 33.6 MB (overlays xb)
    bf16* uwb  = (bf16*)(ws + 67108864);     // 67.1 MB, dead after Bw GEMM
    bf16* qp   = (bf16*)(ws + 67108864);     // 33.6 MB (overlays uwb)
    bf16* Bu   = (bf16*)(ws + 134217728);    // 33.6 MB
    bf16* Bw   = (bf16*)(ws + 167772160);    // 33.6 MB
    bf16* h1   = (bf16*)(ws + 201326592);    // 16.8 MB, dead after h2 GEMM
    bf16* pp   = (bf16*)(ws + 201326592);    // 33.6 MB (overlays h1+h2)
    bf16* h2   = (bf16*)(ws + 218103808);    // 16.8 MB, dead after uw GEMM
    bf16* whb  = (bf16*)(ws + 234881024);    // 8.4 MB
    bf16* wh2b = (bf16*)(ws + 243269632);    // 2.1 MB
    bf16* wyb  = (bf16*)(ws + 245366784);    // 8.4 MB
    bf16* gb   = (bf16*)(ws + 253755392);    // 8.4 MB
    bf16* bmb  = (bf16*)(ws + 262144000);    // 8.4 MB
    bf16* wpb  = (bf16*)(ws + 270532608);    // 8.4 MB
    bf16* wqb  = (bf16*)(ws + 278921216);    // 8.4 MB

    dim3 blk(256);
    auto cast = [&](const float* s, bf16* d, int n) {
        cast_f32_bf16<<<dim3((n / 8 + 255) / 256), blk, 0, stream>>>(s, d, n);
    };
    cast(x,    xb,   BT * NX);
    cast(W_h,  whb,  NR * NX);
    cast(W_h2, wh2b, NR * NR);
    cast(W_y,  wyb,  NX * NR);
    cast(G,    gb,   NB * NB);
    cast(Bm,   bmb,  NB * NB);
    cast(W_p,  wpb,  NB * NB);
    cast(W_q,  wqb,  NB * NB);

    // h1 = relu(x @ W_h^T + b_h)            [8192,1024,K=4096]
    gemm_bt<1, 0, 1><<<dim3(NR / 128, BT / 128), blk, 0, stream>>>(
        xb, NX, whb, NX, b_h, nullptr, 0, h1, NR, BT, NR, NX);
    // h2 = relu(h1 @ W_h2^T + b_h2)         [8192,1024,K=1024]
    gemm_bt<1, 0, 1><<<dim3(NR / 128, BT / 128), blk, 0, stream>>>(
        h1, NR, wh2b, NR, b_h2, nullptr, 0, h2, NR, BT, NR, NR);
    // uw = h2 @ W_y^T + b_y                 [8192,4096,K=1024] -> fp32 d_out + bf16 ws
    gemm_bt<0, 1, 1><<<dim3(NX / 128, BT / 128), blk, 0, stream>>>(
        h2, NR, wyb, NR, b_y, out, NX, uwb, NX, BT, NX, NR);
    // Gu/Gw/Bu/Bw                           [8192,2048,K=2048] each
    gemm_bt<0, 0, 1><<<dim3(NB / 128, BT / 128), blk, 0, stream>>>(
        uwb,      NX, gb,  NB, nullptr, nullptr, 0, Gu, NB, BT, NB, NB);
    gemm_bt<0, 0, 1><<<dim3(NB / 128, BT / 128), blk, 0, stream>>>(
        uwb + NB, NX, gb,  NB, nullptr, nullptr, 0, Gw, NB, BT, NB, NB);
    gemm_bt<0, 0, 1><<<dim3(NB / 128, BT / 128), blk, 0, stream>>>(
        uwb,      NX, bmb, NB, nullptr, nullptr, 0, Bu, NB, BT, NB, NB);
    gemm_bt<0, 0, 1><<<dim3(NB / 128, BT / 128), blk, 0, stream>>>(
        uwb + NB, NX, bmb, NB, nullptr, nullptr, 0, Bw, NB, BT, NB, NB);
    // elementwise combine -> p_pre, q_pre (bf16)
    combine_pq<<<dim3(BT * NB / 4 / 256), blk, 0, stream>>>(
        out, Gu, Gw, Bu, Bw, bias_p, bias_q, pp, qp);
    // p = p_pre @ W_p^T + b_p -> d_out[33554432..]
    gemm_bt<0, 1, 0><<<dim3(NB / 128, BT / 128), blk, 0, stream>>>(
        pp, NB, wpb, NB, b_p, out + (size_t)BT * NX, NB, nullptr, 0, BT, NB, NB);
    // q = q_pre @ W_q^T + b_q -> d_out[50331648..]
    gemm_bt<0, 1, 0><<<dim3(NB / 128, BT / 128), blk, 0, stream>>>(
        qp, NB, wqb, NB, b_q, out + (size_t)BT * NX + (size_t)BT * NB, NB, nullptr, 0, BT, NB, NB);
}

// Round 2
// 1205.321 us; speedup vs baseline: 1.0306x; 1.0306x over previous
//
#include <hip/hip_runtime.h>

typedef __bf16 bf16;
typedef __bf16 bf16x8 __attribute__((ext_vector_type(8)));
typedef __bf16 bf16x4 __attribute__((ext_vector_type(4)));
typedef float  f32x4  __attribute__((ext_vector_type(4)));

__device__ __forceinline__ void async_load16(const void* g, void* l) {
    __builtin_amdgcn_global_load_lds(
        (const __attribute__((address_space(1))) void*)g,
        (__attribute__((address_space(3))) void*)l,
        16, 0, 0);
}

// ---------------- cast fp32 -> bf16, 8 elems/thread ----------------
__global__ __launch_bounds__(256) void cast_f32_bf16(
        const float* __restrict__ s, bf16* __restrict__ d, int n) {
    int i = (blockIdx.x * 256 + threadIdx.x) * 8;
    if (i >= n) return;
    f32x4 v0 = *(const f32x4*)(s + i);
    f32x4 v1 = *(const f32x4*)(s + i + 4);
    bf16x8 o;
    o[0] = (bf16)v0[0]; o[1] = (bf16)v0[1]; o[2] = (bf16)v0[2]; o[3] = (bf16)v0[3];
    o[4] = (bf16)v1[0]; o[5] = (bf16)v1[1]; o[6] = (bf16)v1[2]; o[7] = (bf16)v1[3];
    *(bf16x8*)(d + i) = o;
}

// ---------------- diagnostic fill (ws too small) ----------------
__global__ __launch_bounds__(256) void fill_f32(float* p, float v, int n) {
    int i = blockIdx.x * 256 + threadIdx.x;
    if (i < n) p[i] = v;
}

// ---------------- GEMM: C[M,N] = A[M,K] * B[N,K]^T (+bias, relu) ----------------
// m97-style: 128x128 tile, 4 waves 2x2 (each 64x64), BK=32, 16x16x32 bf16 MFMA,
// global_load_lds width-16 staging, 2-barrier K-loop.
// __launch_bounds__(256,3): 3 waves/EU min -> 3 blocks/CU (m97's occupancy);
// VGPR budget ~170, kernel needs ~120 -> no spill.
template<int RELU, int WF32, int WBF16>
__global__ __launch_bounds__(256, 3) void gemm_bt(
        const bf16* __restrict__ A, int lda,
        const bf16* __restrict__ B, int ldb,
        const float* __restrict__ bias,
        float* __restrict__ Cf, int ldcf,
        bf16* __restrict__ Cb, int ldcb,
        int M, int N, int K) {
    (void)M; (void)N;
    __shared__ __attribute__((aligned(16))) bf16 lA[128 * 32];
    __shared__ __attribute__((aligned(16))) bf16 lB[128 * 32];

    const int t = threadIdx.x;
    const int w = t >> 6, lane = t & 63;
    const int wm = w >> 1, wn = w & 1;
    const int m0 = blockIdx.y * 128, n0 = blockIdx.x * 128;
    const int lane15 = lane & 15, quad = lane >> 4;

    f32x4 acc[4][4] = {};

    // staging: per wave, 2 chunks of 16 rows for A and for B.
    // within a chunk: lane i -> row i/4, col-elem (i&3)*8 (lane i writes LDS base+16*i)
    const int srow = lane >> 2;
    const int scol = (lane & 3) * 8;
    const int c0 = 2 * w, c1 = 2 * w + 1;
    const bf16* gA0 = A + (size_t)(m0 + c0 * 16 + srow) * lda + scol;
    const bf16* gA1 = A + (size_t)(m0 + c1 * 16 + srow) * lda + scol;
    const bf16* gB0 = B + (size_t)(n0 + c0 * 16 + srow) * ldb + scol;
    const bf16* gB1 = B + (size_t)(n0 + c1 * 16 + srow) * ldb + scol;
    bf16* lA0 = &lA[c0 * 512];
    bf16* lA1 = &lA[c1 * 512];
    bf16* lB0 = &lB[c0 * 512];
    bf16* lB1 = &lB[c1 * 512];

    // fragment read base: A row = wm*64 + i*16 + lane15, k = quad*8
    const bf16* fA = &lA[(wm * 64 + lane15) * 32 + quad * 8];
    const bf16* fB = &lB[(wn * 64 + lane15) * 32 + quad * 8];

    for (int k0 = 0; k0 < K; k0 += 32) {
        async_load16(gA0, lA0);
        async_load16(gA1, lA1);
        async_load16(gB0, lB0);
        async_load16(gB1, lB1);
        gA0 += 32; gA1 += 32; gB0 += 32; gB1 += 32;
        __syncthreads();   // drains vmcnt before any ds_read
        bf16x8 a[4], b[4];
#pragma unroll
        for (int i = 0; i < 4; i++) a[i] = *(const bf16x8*)(fA + i * 16 * 32);
#pragma unroll
        for (int j = 0; j < 4; j++) b[j] = *(const bf16x8*)(fB + j * 16 * 32);
#pragma unroll
        for (int i = 0; i < 4; i++)
#pragma unroll
            for (int j = 0; j < 4; j++)
                acc[i][j] = __builtin_amdgcn_mfma_f32_16x16x32_bf16(a[i], b[j], acc[i][j], 0, 0, 0);
        __syncthreads();   // compute done before next stage overwrites LDS
    }

    // epilogue: D[row=quad*4+r][col=lane15] per 16x16 tile
#pragma unroll
    for (int i = 0; i < 4; i++) {
        int row = m0 + wm * 64 + i * 16 + quad * 4;
#pragma unroll
        for (int j = 0; j < 4; j++) {
            int col = n0 + wn * 64 + j * 16 + lane15;
            float bv = bias ? bias[col] : 0.0f;
#pragma unroll
            for (int r = 0; r < 4; r++) {
                float v = acc[i][j][r] + bv;
                if (RELU) v = v > 0.0f ? v : 0.0f;
                if (WF32)  Cf[(size_t)(row + r) * ldcf + col] = v;
                if (WBF16) Cb[(size_t)(row + r) * ldcb + col] = (bf16)v;
            }
        }
    }
}

// ---------------- elementwise combine -> p_pre, q_pre (bf16) ----------------
// GBu[b, 0:2048] = Gu, GBu[b, 2048:4096] = Bu (stacked [G;Bm] weight GEMM)
// GBw likewise for the w rows. u,w read from bf16 uwb (halves HBM read vs fp32).
__global__ __launch_bounds__(256) void combine_pq(
        const bf16* __restrict__ uwb,          // 8192 x 4096 bf16 (u | w)
        const bf16* __restrict__ GBu, const bf16* __restrict__ GBw,
        const float* __restrict__ bias_p, const float* __restrict__ bias_q,
        bf16* __restrict__ pp, bf16* __restrict__ qp) {
    int idx = (blockIdx.x * 256 + threadIdx.x) * 4;   // into 8192x2048
    int row = idx >> 11;
    int col = idx & 2047;
    size_t base = (size_t)row * 4096 + col;
    bf16x4 u4  = *(const bf16x4*)(uwb + base);
    bf16x4 w4  = *(const bf16x4*)(uwb + base + 2048);
    bf16x4 gu4 = *(const bf16x4*)(GBu + base);
    bf16x4 bu4 = *(const bf16x4*)(GBu + base + 2048);
    bf16x4 gw4 = *(const bf16x4*)(GBw + base);
    bf16x4 bw4 = *(const bf16x4*)(GBw + base + 2048);
    bf16x4 po, qo;
#pragma unroll
    for (int r = 0; r < 4; r++) {
        float u = (float)u4[r], w = (float)w4[r];
        float gu = (float)gu4[r], gw = (float)gw4[r];
        float bu = (float)bu4[r], bw = (float)bw4[r];
        float p = u * gu + w * gw + w * bu - u * bw + bias_p[col + r];
        float q = w * gu - u * gw - u * bu - w * bw + bias_q[col + r];
        po[r] = (bf16)p;
        qo[r] = (bf16)q;
    }
    *(bf16x4*)(pp + idx) = po;
    *(bf16x4*)(qp + idx) = qo;
}

extern "C" void kernel_launch(void* const* d_in, const int* in_sizes, int n_in,
                              void* d_out, int out_size, void* d_ws, size_t ws_size,
                              hipStream_t stream) {
    (void)in_sizes; (void)n_in;
    const int BT = 8192, NX = 4096, NR = 1024, NB = 2048;

    const float* x      = (const float*)d_in[0];
    const float* W_h    = (const float*)d_in[1];
    const float* b_h    = (const float*)d_in[2];
    const float* W_h2   = (const float*)d_in[3];
    const float* b_h2   = (const float*)d_in[4];
    const float* W_y    = (const float*)d_in[5];
    const float* b_y    = (const float*)d_in[6];
    const float* G      = (const float*)d_in[7];
    const float* Bm     = (const float*)d_in[8];
    const float* bias_p = (const float*)d_in[9];
    const float* bias_q = (const float*)d_in[10];
    const float* W_p    = (const float*)d_in[11];
    const float* b_p    = (const float*)d_in[12];
    const float* W_q    = (const float*)d_in[13];
    const float* b_q    = (const float*)d_in[14];
    float* out = (float*)d_out;

    // ---- workspace layout (bytes), lifetime-based aliasing ----
    const size_t NEED = 320864256ull;  // ~321 MB
    if (ws_size < NEED) {  // diagnostic: report available MB via d_out
        fill_f32<<<dim3((out_size + 255) / 256), dim3(256), 0, stream>>>(
            out, (float)(ws_size >> 20), out_size);
        return;
    }
    char* ws = (char*)d_ws;
    bf16* xb   = (bf16*)(ws + 0);            // 67.1 MB, dead after h1 GEMM
    bf16* GBu  = (bf16*)(ws + 0);            // 67.1 MB (overlays xb)
    bf16* uwb  = (bf16*)(ws + 67108864);     // 67.1 MB, live through combine
    bf16* GBw  = (bf16*)(ws + 134217728);    // 67.1 MB
    bf16* h1   = (bf16*)(ws + 201326592);    // 16.8 MB, dead after h2 GEMM
    bf16* pp   = (bf16*)(ws + 201326592);    // 33.6 MB (overlays h1+h2, both dead)
    bf16* h2   = (bf16*)(ws + 218103808);    // 16.8 MB, dead after uw GEMM
    bf16* qp   = (bf16*)(ws + 234881024);    // 33.6 MB
    bf16* whb  = (bf16*)(ws + 268435456);    // 8.4 MB
    bf16* wh2b = (bf16*)(ws + 276824064);    // 2.1 MB
    bf16* wyb  = (bf16*)(ws + 278921216);    // 8.4 MB
    bf16* gbm  = (bf16*)(ws + 287309824);    // 16.8 MB: [G; Bm] stacked (4096 x 2048)
    bf16* wpb  = (bf16*)(ws + 304087040);    // 8.4 MB
    bf16* wqb  = (bf16*)(ws + 312475648);    // 8.4 MB

    dim3 blk(256);
    auto cast = [&](const float* s, bf16* d, int n) {
        cast_f32_bf16<<<dim3((n / 8 + 255) / 256), blk, 0, stream>>>(s, d, n);
    };
    cast(x,    xb,   BT * NX);
    cast(W_h,  whb,  NR * NX);
    cast(W_h2, wh2b, NR * NR);
    cast(W_y,  wyb,  NX * NR);
    cast(G,    gbm,            NB * NB);   // rows 0..2047 of stacked weight
    cast(Bm,   gbm + (size_t)NB * NB, NB * NB);   // rows 2048..4095
    cast(W_p,  wpb,  NB * NB);
    cast(W_q,  wqb,  NB * NB);

    // h1 = relu(x @ W_h^T + b_h)            [8192,1024,K=4096]
    gemm_bt<1, 0, 1><<<dim3(NR / 128, BT / 128), blk, 0, stream>>>(
        xb, NX, whb, NX, b_h, nullptr, 0, h1, NR, BT, NR, NX);
    // h2 = relu(h1 @ W_h2^T + b_h2)         [8192,1024,K=1024]
    gemm_bt<1, 0, 1><<<dim3(NR / 128, BT / 128), blk, 0, stream>>>(
        h1, NR, wh2b, NR, b_h2, nullptr, 0, h2, NR, BT, NR, NR);
    // uw = h2 @ W_y^T + b_y                 [8192,4096,K=1024] -> fp32 d_out + bf16 ws
    gemm_bt<0, 1, 1><<<dim3(NX / 128, BT / 128), blk, 0, stream>>>(
        h2, NR, wyb, NR, b_y, out, NX, uwb, NX, BT, NX, NR);
    // GBu = u @ [G;Bm]^T, GBw = w @ [G;Bm]^T   [8192,4096,K=2048] each
    gemm_bt<0, 0, 1><<<dim3(NX / 128, BT / 128), blk, 0, stream>>>(
        uwb,      NX, gbm, NB, nullptr, nullptr, 0, GBu, NX, BT, NX, NB);
    gemm_bt<0, 0, 1><<<dim3(NX / 128, BT / 128), blk, 0, stream>>>(
        uwb + NB, NX, gbm, NB, nullptr, nullptr, 0, GBw, NX, BT, NX, NB);
    // elementwise combine -> p_pre, q_pre (bf16)
    combine_pq<<<dim3(BT * NB / 4 / 256), blk, 0, stream>>>(
        uwb, GBu, GBw, bias_p, bias_q, pp, qp);
    // p = p_pre @ W_p^T + b_p -> d_out[33554432..]
    gemm_bt<0, 1, 0><<<dim3(NB / 128, BT / 128), blk, 0, stream>>>(
        pp, NB, wpb, NB, b_p, out + (size_t)BT * NX, NB, nullptr, 0, BT, NB, NB);
    // q = q_pre @ W_q^T + b_q -> d_out[50331648..]
    gemm_bt<0, 1, 0><<<dim3(NB / 128, BT / 128), blk, 0, stream>>>(
        qp, NB, wqb, NB, b_q, out + (size_t)BT * NX + (size_t)BT * NB, NB, nullptr, 0, BT, NB, NB);
}